// Round 12
// baseline (134.912 us; speedup 1.0000x reference)
//
#include <hip/hip_runtime.h>

// Problem: A=8, B=16, N=M=1024, K=64. u:(A,B,N,K) f32, v:(A,B,M,K) f32.
// out0 = u * (dot(u_row, v_sum) > 0), out1 = v * (dot(v_row, u_sum) > 0)
//
// Round-15: fused pair-interleaved traversal + LDS stash (spill-proof).
// Evidence so far:
//   R8: same-order traversal -> FETCH 66.3 MB (= unique volume). PROVEN.
//   R1: register retention of own rows -> no 2nd read pass, 28.8 us, and
//       (from session totals 114 vs 150) NO spill. PROVEN.
//   R6/R8/R9: the compiler's occupancy heuristic sometimes caps this kernel
//       shape at 64 VGPRs (2x1024-thread blocks/CU target) and spills the
//       64-reg stash -> WRITE 129 MB, ~67 us. __launch_bounds__(1024,4)
//       does NOT lift the cap (R9). Coin flip; stop flipping it.
//   R11: re-read instead of retention costs ~8 us (32 vs 28.8). Retain.
// This kernel:
//   - ONE loop: iter i loads own-row AND other-row (io_oth = io_own ^ 8192).
//     At iter i the two pair-blocks touch the SAME two rows (own/other
//     swapped) -> reuse distance ~= CU skew -> duplicate reads L2-collapse
//     (tighter than R8's same-order). No branches.
//   - u own rows stashed in LDS (8 x 1024 float4 = 128 KB), v own rows in
//     vr[8] (32 VGPRs). Live set ~60 regs: fits even a 64-VGPR cap.
//     136 KB LDS also forces 1 block/CU -> backend sees LDS-limited
//     occupancy -> VGPR budget relaxes to 128 anyway. No spill either way.
// Traffic: FETCH ~64-70 MB, WRITE ~64-67 MB -> ~134 MB HBM ~= 22.4 us floor;
// predicted kernel ~23-26 us, total ~108-111.

#define NBATCH 128        // A*B
#define NROW   1024       // N == M
#define KDIM   64
#define ELEMS_PER_TENSOR (128ull * 1024ull * 64ull)  // 8388608

typedef float floatx4 __attribute__((ext_vector_type(4)));  // for nontemporal builtin

__global__ __launch_bounds__(1024)
void fused_ldsstash_kernel(const float* __restrict__ u,
                           const float* __restrict__ v,
                           float* __restrict__ out) {
    const int bid   = blockIdx.x;        // 0..255 (1 block/CU)
    // Same-XCD pair swizzle: HW places block bid on XCD (bid & 7); pair
    // blocks (batch, half 0/1) are bids (i, i+8) -> same XCD -> shared L2.
    const int xcd   = bid & 7;
    const int slot  = bid >> 3;          // 0..31
    const int batch = xcd * 16 + (slot >> 1);  // 0..127
    const int half  = slot & 1;          // own rows: [half*512, half*512+512)
    const int tid   = threadIdx.x;       // 0..1023
    const int k4    = tid & 15;          // float4 column group (16 x 4 = 64 cols)
    const int rg    = tid >> 4;          // 0..63 row group
    const int wave  = tid >> 6;          // 0..15

    const size_t boff = (size_t)batch * NROW * KDIM;
    const float4* ub = (const float4*)(u + boff);
    const float4* vb = (const float4*)(v + boff);
    float* ou = out + boff;
    float* ov = out + ELEMS_PER_TENSOR + boff;

    // 128 KB u-row stash + 8 KB reduce scratch = 136 KB static LDS
    // (forces 1 block/CU; gfx950 pool is 160 KB).
    __shared__ float4 ustash[8][1024];   // [i][tid]
    __shared__ float4 red_u[16][16];     // [wave][k4]
    __shared__ float4 red_v[16][16];

    // ---- Phase A: fused pair-interleaved read of the whole batch ----------
    // Own row (stash) and other row (accum only) in the SAME iteration.
    // own/other differ only in the half bit: io_oth = io_own ^ 8192
    // (8192 float4 = 512 rows x 16 float4/row).
    const int r_own0 = half * 512 + rg;
    float4 vr[8];
    float4 su = make_float4(0.f, 0.f, 0.f, 0.f);
    float4 sv = make_float4(0.f, 0.f, 0.f, 0.f);
    #pragma unroll
    for (int i = 0; i < 8; ++i) {
        size_t io  = (size_t)(r_own0 + 64 * i) * 16 + k4;  // wave: 4 rows x 1KB
        size_t ix  = io ^ 8192;                             // other-half row
        float4 uo = ub[io];
        float4 ux = ub[ix];
        float4 vo = vb[io];
        float4 vx = vb[ix];
        ustash[i][tid] = uo;             // u own -> LDS
        vr[i] = vo;                      // v own -> regs
        su.x += uo.x + ux.x; su.y += uo.y + ux.y;
        su.z += uo.z + ux.z; su.w += uo.w + ux.w;
        sv.x += vo.x + vx.x; sv.y += vo.y + vx.y;
        sv.z += vo.z + vx.z; sv.w += vo.w + vx.w;
    }

    // ---- Reduce: shfl across the 4 row-groups within each wave ------------
    su.x += __shfl_xor(su.x, 16); su.y += __shfl_xor(su.y, 16);
    su.z += __shfl_xor(su.z, 16); su.w += __shfl_xor(su.w, 16);
    su.x += __shfl_xor(su.x, 32); su.y += __shfl_xor(su.y, 32);
    su.z += __shfl_xor(su.z, 32); su.w += __shfl_xor(su.w, 32);
    sv.x += __shfl_xor(sv.x, 16); sv.y += __shfl_xor(sv.y, 16);
    sv.z += __shfl_xor(sv.z, 16); sv.w += __shfl_xor(sv.w, 16);
    sv.x += __shfl_xor(sv.x, 32); sv.y += __shfl_xor(sv.y, 32);
    sv.z += __shfl_xor(sv.z, 32); sv.w += __shfl_xor(sv.w, 32);

    if ((tid & 63) < 16) {               // lanes 0..15 hold k4 = lane
        red_u[wave][k4] = su;
        red_v[wave][k4] = sv;
    }
    __syncthreads();                     // the ONLY barrier (also covers stash)

    // all-thread self-reduce; same-k4 threads read same address (broadcast)
    float4 us = make_float4(0.f, 0.f, 0.f, 0.f);  // u colsum (masks v rows)
    float4 vs = make_float4(0.f, 0.f, 0.f, 0.f);  // v colsum (masks u rows)
    #pragma unroll
    for (int w = 0; w < 16; ++w) {
        float4 a = red_u[w][k4];
        float4 b = red_v[w][k4];
        us.x += a.x; us.y += a.y; us.z += a.z; us.w += a.w;
        vs.x += b.x; vs.y += b.y; vs.z += b.z; vs.w += b.w;
    }

    // ---- Phase B: mask own half (u from LDS, v from regs), NT stores ------
    #pragma unroll
    for (int i = 0; i < 8; ++i) {
        size_t io = (size_t)(r_own0 + 64 * i) * 16 + k4;

        float4 a = ustash[i][tid];       // contiguous 1KB/wave ds_read_b128
        float pu = a.x * vs.x + a.y * vs.y + a.z * vs.z + a.w * vs.w;
        pu += __shfl_xor(pu, 1);
        pu += __shfl_xor(pu, 2);
        pu += __shfl_xor(pu, 4);
        pu += __shfl_xor(pu, 8);         // full 64-col dot across the 16 k4 lanes
        float mu = (pu > 0.f) ? 1.f : 0.f;
        floatx4 outu = { a.x * mu, a.y * mu, a.z * mu, a.w * mu };
        __builtin_nontemporal_store(outu, (floatx4*)(ou + io * 4));

        float pv = vr[i].x * us.x + vr[i].y * us.y + vr[i].z * us.z + vr[i].w * us.w;
        pv += __shfl_xor(pv, 1);
        pv += __shfl_xor(pv, 2);
        pv += __shfl_xor(pv, 4);
        pv += __shfl_xor(pv, 8);
        float mv = (pv > 0.f) ? 1.f : 0.f;
        floatx4 outv = { vr[i].x * mv, vr[i].y * mv, vr[i].z * mv, vr[i].w * mv };
        __builtin_nontemporal_store(outv, (floatx4*)(ov + io * 4));
    }
}

extern "C" void kernel_launch(void* const* d_in, const int* in_sizes, int n_in,
                              void* d_out, int out_size, void* d_ws, size_t ws_size,
                              hipStream_t stream) {
    const float* u = (const float*)d_in[0];
    const float* v = (const float*)d_in[1];
    float* out = (float*)d_out;

    fused_ldsstash_kernel<<<dim3(256), dim3(1024), 0, stream>>>(u, v, out);
}